// Round 1
// baseline (428.289 us; speedup 1.0000x reference)
//
#include <hip/hip_runtime.h>

#define H_IMG 200
#define W_IMG 200
#define NTOK  40000       // H*W
#define BATCH 2
#define ROWS  80000       // B*N
#define DMODEL 256
#define HEADS 8
#define HD 32
#define NPTS 4

typedef __attribute__((ext_vector_type(8))) short bf16x8;
typedef __attribute__((ext_vector_type(4))) float f32x4;

__device__ __forceinline__ unsigned short f2bf(float f) {
  unsigned u = __float_as_uint(f);
  u += 0x7fffu + ((u >> 16) & 1u);
  return (unsigned short)(u >> 16);
}
__device__ __forceinline__ float bfl(unsigned u) { return __uint_as_float(u << 16); }
__device__ __forceinline__ float bfh(unsigned u) { return __uint_as_float(u & 0xffff0000u); }

// ---------------------------------------------------------------- prep ------
// Transpose + convert weights to bf16: Wt[n][k] = bf16(W[k][n]).
__global__ __launch_bounds__(256) void prep_weights(
    const float* __restrict__ W_val, const float* __restrict__ W_off,
    const float* __restrict__ W_attn, const float* __restrict__ W_out,
    unsigned short* __restrict__ Wv_t, unsigned short* __restrict__ Wca_t,
    unsigned short* __restrict__ Wo_t)
{
  int tid = blockIdx.x * 256 + threadIdx.x;   // 0..65535
  int n = tid >> 8, k = tid & 255;
  Wv_t[n * 256 + k] = f2bf(W_val[k * 256 + n]);
  Wo_t[n * 256 + k] = f2bf(W_out[k * 256 + n]);
  if (tid < 96 * 256) {
    float w = (n < 64) ? W_off[k * 64 + n] : W_attn[k * 32 + (n - 64)];
    Wca_t[tid] = f2bf(w);
  }
}

// ---------------------------------------------------------------- GEMM ------
// C[64 x NT*16] = A[64 x 256] @ B[256 x NT*16], K fully staged, 4 waves.
// AMODE: 0 = A from f32 Af0; 1 = A from Af0+Af1; 2 = A already bf16 (Abf).
// EPI:   0 = store bf16 with bias (v);
//        1 = store f32 with bias; cols>=64 get per-head softmax-4 (proj);
//        2 = store f32 with bias + residual xres (final out).
template<int NT, int AMODE, int EPI>
__global__ __launch_bounds__(256, 2) void gemm_k(
    const float* __restrict__ Af0, const float* __restrict__ Af1,
    const unsigned short* __restrict__ Abf,
    const unsigned short* __restrict__ Bt,     // [ncols][256] bf16 (transposed)
    const float* __restrict__ bias0, const float* __restrict__ bias1,
    const float* __restrict__ xres,
    float* __restrict__ outf, unsigned short* __restrict__ outb)
{
  __shared__ unsigned short As[64][264];        // +8 pad: 2-way-max LDS banks
  __shared__ unsigned short Bs[NT * 16][264];
  const int tid = threadIdx.x;
  const int m0 = blockIdx.x * 64;
  const int n0 = blockIdx.y * (NT * 16);

  if (AMODE == 2) {
#pragma unroll
    for (int j = 0; j < 8; ++j) {
      int flat = tid + j * 256;                 // 16B units, 2048 total
      int row = flat >> 5, seg = flat & 31;
      uint4 u = *(const uint4*)(Abf + (size_t)(m0 + row) * 256 + seg * 8);
      *(uint4*)&As[row][seg * 8] = u;
    }
  } else {
#pragma unroll
    for (int j = 0; j < 16; ++j) {
      int flat = tid + j * 256;                 // float4 units, 4096 total
      int row = flat >> 6, seg = flat & 63;
      size_t gi = (size_t)(m0 + row) * 256 + seg * 4;
      float4 a = *(const float4*)(Af0 + gi);
      if (AMODE == 1) {
        float4 b = *(const float4*)(Af1 + gi);
        a.x += b.x; a.y += b.y; a.z += b.z; a.w += b.w;
      }
      unsigned lo = (unsigned)f2bf(a.x) | ((unsigned)f2bf(a.y) << 16);
      unsigned hi = (unsigned)f2bf(a.z) | ((unsigned)f2bf(a.w) << 16);
      *(uint2*)&As[row][seg * 4] = make_uint2(lo, hi);
    }
  }
#pragma unroll
  for (int j = 0; j < NT * 2; ++j) {
    int flat = tid + j * 256;
    int row = flat >> 5, seg = flat & 31;
    uint4 u = *(const uint4*)(Bt + (size_t)(n0 + row) * 256 + seg * 8);
    *(uint4*)&Bs[row][seg * 8] = u;
  }
  __syncthreads();

  const int wave = tid >> 6;
  const int lane = tid & 63;
  const int lr = lane & 15;       // A row / B col / D col
  const int lk = lane >> 4;       // k-group; D row group
  f32x4 acc[NT];
#pragma unroll
  for (int nt = 0; nt < NT; ++nt) acc[nt] = (f32x4){0.f, 0.f, 0.f, 0.f};

#pragma unroll
  for (int kt = 0; kt < 8; ++kt) {
    bf16x8 af = *(const bf16x8*)&As[wave * 16 + lr][kt * 32 + lk * 8];
#pragma unroll
    for (int nt = 0; nt < NT; ++nt) {
      bf16x8 bfr = *(const bf16x8*)&Bs[nt * 16 + lr][kt * 32 + lk * 8];
      acc[nt] = __builtin_amdgcn_mfma_f32_16x16x32_bf16(af, bfr, acc[nt], 0, 0, 0);
    }
  }

#pragma unroll
  for (int nt = 0; nt < NT; ++nt) {
    const int gcol = n0 + nt * 16 + lr;
    float bias = (EPI == 1) ? ((gcol < 64) ? bias0[gcol] : bias1[gcol - 64])
                            : bias0[gcol];
#pragma unroll
    for (int r = 0; r < 4; ++r) {
      const int grow = m0 + wave * 16 + lk * 4 + r;
      float val = acc[nt][r] + bias;
      if (EPI == 0) {
        outb[(size_t)grow * 256 + gcol] = f2bf(val);
      } else if (EPI == 2) {
        size_t gi = (size_t)grow * 256 + gcol;
        outf[gi] = val + xres[gi];
      } else {
        if (gcol >= 64) {   // wave-uniform per nt (16-col tiles)
          float m1 = fmaxf(val, __shfl_xor(val, 1));
          float mx = fmaxf(m1, __shfl_xor(m1, 2));
          float e = __expf(val - mx);
          float s1 = e + __shfl_xor(e, 1);
          float s = s1 + __shfl_xor(s1, 2);
          val = e / s;
        }
        outf[(size_t)grow * 96 + gcol] = val;
      }
    }
  }
}

// -------------------------------------------------------------- sample ------
// One thread = one (token, head). smp[t][0..63] raw offsets, [64..95] softmaxed
// attn. px = col + off_x, py = row + off_y (exact collapse of ref-point math).
__global__ __launch_bounds__(256, 4) void sample_k(
    const unsigned short* __restrict__ vbf,    // [B][NTOK][256] bf16
    const float* __restrict__ smp,             // [ROWS][96]
    unsigned short* __restrict__ sampled)      // [ROWS][256] bf16
{
  const int tid = blockIdx.x * 256 + threadIdx.x;
  const int t = tid >> 3;
  const int h = tid & 7;
  const int b = t / NTOK;
  const int n = t - b * NTOK;
  const int ry = n / W_IMG;
  const int cx = n - ry * W_IMG;
  const float* sp = smp + (size_t)t * 96;
  const unsigned short* vb = vbf + (size_t)b * NTOK * 256 + h * 32;

  float acc[32];
#pragma unroll
  for (int i = 0; i < 32; ++i) acc[i] = 0.f;

#pragma unroll
  for (int p = 0; p < 4; ++p) {
    float ox = sp[h * 8 + p * 2 + 0];
    float oy = sp[h * 8 + p * 2 + 1];
    float aw = sp[64 + h * 4 + p];
    float px = (float)cx + ox;
    float py = (float)ry + oy;
    float fx = floorf(px), fy = floorf(py);
    int x0 = (int)fx, y0 = (int)fy;
    float lx = px - fx, ly = py - fy;
    float w00 = (1.f - lx) * (1.f - ly) * aw;
    float w10 = lx * (1.f - ly) * aw;
    float w01 = (1.f - lx) * ly * aw;
    float w11 = lx * ly * aw;
#pragma unroll
    for (int cc = 0; cc < 4; ++cc) {
      int ix = x0 + (cc & 1);
      int iy = y0 + (cc >> 1);
      float w = (cc == 0) ? w00 : (cc == 1) ? w10 : (cc == 2) ? w01 : w11;
      if (ix >= 0 && ix < W_IMG && iy >= 0 && iy < H_IMG) {
        const unsigned short* g = vb + (size_t)(iy * W_IMG + ix) * 256;
#pragma unroll
        for (int q = 0; q < 4; ++q) {
          uint4 u = *(const uint4*)(g + q * 8);
          acc[q * 8 + 0] += w * bfl(u.x); acc[q * 8 + 1] += w * bfh(u.x);
          acc[q * 8 + 2] += w * bfl(u.y); acc[q * 8 + 3] += w * bfh(u.y);
          acc[q * 8 + 4] += w * bfl(u.z); acc[q * 8 + 5] += w * bfh(u.z);
          acc[q * 8 + 6] += w * bfl(u.w); acc[q * 8 + 7] += w * bfh(u.w);
        }
      }
    }
  }
  unsigned uo[16];
#pragma unroll
  for (int i = 0; i < 16; ++i)
    uo[i] = (unsigned)f2bf(acc[2 * i]) | ((unsigned)f2bf(acc[2 * i + 1]) << 16);
  uint4* dst = (uint4*)(sampled + (size_t)t * 256 + h * 32);
  dst[0] = make_uint4(uo[0], uo[1], uo[2], uo[3]);
  dst[1] = make_uint4(uo[4], uo[5], uo[6], uo[7]);
  dst[2] = make_uint4(uo[8], uo[9], uo[10], uo[11]);
  dst[3] = make_uint4(uo[12], uo[13], uo[14], uo[15]);
}

// -------------------------------------------------------------- launch ------
extern "C" void kernel_launch(void* const* d_in, const int* in_sizes, int n_in,
                              void* d_out, int out_size, void* d_ws, size_t ws_size,
                              hipStream_t stream) {
  const float* x      = (const float*)d_in[0];
  const float* x_pos  = (const float*)d_in[1];
  const float* W_off  = (const float*)d_in[2];
  const float* b_off  = (const float*)d_in[3];
  const float* W_attn = (const float*)d_in[4];
  const float* b_attn = (const float*)d_in[5];
  const float* W_val  = (const float*)d_in[6];
  const float* b_val  = (const float*)d_in[7];
  const float* W_out  = (const float*)d_in[8];
  const float* b_out  = (const float*)d_in[9];
  float* out = (float*)d_out;

  char* ws = (char*)d_ws;
  unsigned short* Wv_t    = (unsigned short*)(ws);                 // 131072 B
  unsigned short* Wo_t    = (unsigned short*)(ws + 131072);        // 131072 B
  unsigned short* Wca_t   = (unsigned short*)(ws + 262144);        //  49152 B
  unsigned short* vbf     = (unsigned short*)(ws + 311296);        // 40.96 MB
  float*          smp     = (float*)(ws + 41271296);               // 30.72 MB
  unsigned short* sampled = (unsigned short*)(ws + 71991296);      // 40.96 MB
  // total ws use: 112,951,296 B

  prep_weights<<<256, 256, 0, stream>>>(W_val, W_off, W_attn, W_out,
                                        Wv_t, Wca_t, Wo_t);
  // v = x @ W_val + b_val  -> bf16
  gemm_k<4, 0, 0><<<dim3(1250, 4), 256, 0, stream>>>(
      x, nullptr, nullptr, Wv_t, b_val, nullptr, nullptr, nullptr, vbf);
  // proj = (x+x_pos) @ [W_off|W_attn] + bias, softmax on attn cols -> f32
  gemm_k<6, 1, 1><<<dim3(1250, 1), 256, 0, stream>>>(
      x, x_pos, nullptr, Wca_t, b_off, b_attn, nullptr, smp, nullptr);
  // bilinear gather
  sample_k<<<2500, 256, 0, stream>>>(vbf, smp, sampled);
  // out = x + sampled @ W_out + b_out
  gemm_k<4, 2, 2><<<dim3(1250, 4), 256, 0, stream>>>(
      nullptr, nullptr, sampled, Wo_t, b_out, nullptr, x, out, nullptr);
}

// Round 2
// 363.075 us; speedup vs baseline: 1.1796x; 1.1796x over previous
//
#include <hip/hip_runtime.h>

#define H_IMG 200
#define W_IMG 200
#define NTOK  40000       // H*W
#define ROWS  80000       // B*N
#define HEADS 8

typedef __attribute__((ext_vector_type(8))) short bf16x8;
typedef __attribute__((ext_vector_type(4))) float f32x4;

__device__ __forceinline__ unsigned short f2bf(float f) {
  unsigned u = __float_as_uint(f);
  u += 0x7fffu + ((u >> 16) & 1u);
  return (unsigned short)(u >> 16);
}
__device__ __forceinline__ float bfl(unsigned u) { return __uint_as_float(u << 16); }
__device__ __forceinline__ float bfh(unsigned u) { return __uint_as_float(u & 0xffff0000u); }

// ---------------------------------------------------------------- prep ------
// Transpose + convert weights to bf16: Wt[n][k] = bf16(W[k][n]). Also build
// combined proj bias biasc[96] = [b_off | b_attn].
__global__ __launch_bounds__(256) void prep_weights(
    const float* __restrict__ W_val, const float* __restrict__ W_off,
    const float* __restrict__ W_attn, const float* __restrict__ W_out,
    const float* __restrict__ b_off, const float* __restrict__ b_attn,
    unsigned short* __restrict__ Wv_t, unsigned short* __restrict__ Wca_t,
    unsigned short* __restrict__ Wo_t, float* __restrict__ biasc)
{
  int tid = blockIdx.x * 256 + threadIdx.x;   // 0..65535
  int n = tid >> 8, k = tid & 255;
  Wv_t[n * 256 + k] = f2bf(W_val[k * 256 + n]);
  Wo_t[n * 256 + k] = f2bf(W_out[k * 256 + n]);
  if (tid < 96 * 256) {
    float w = (n < 64) ? W_off[k * 64 + n] : W_attn[k * 32 + (n - 64)];
    Wca_t[tid] = f2bf(w);
  }
  if (tid < 96) biasc[tid] = (tid < 64) ? b_off[tid] : b_attn[tid - 64];
}

// ---------------------------------------------------------------- GEMM ------
// Single-pass-A: block owns 64 rows x (NCHUNK*NT*16) cols; A staged once in
// LDS, B chunk restaged per iteration (weights are L2-resident).
// AMODE: 0 = A from f32 Af0; 1 = A from Af0+Af1; 2 = A already bf16 (Abf).
// EPI:   0 = store bf16 with bias (v);
//        1 = store f32 with bias; cols>=64 get per-head softmax-4 (proj);
//        2 = store f32 with bias + residual xres (final out).
template<int NCHUNK, int NT, int AMODE, int EPI>
__global__ __launch_bounds__(256, 2) void gemm_wide(
    const float* __restrict__ Af0, const float* __restrict__ Af1,
    const unsigned short* __restrict__ Abf,
    const unsigned short* __restrict__ Bt,     // [ncols][256] bf16 (transposed)
    const float* __restrict__ bias, const float* __restrict__ xres,
    float* __restrict__ outf, unsigned short* __restrict__ outb)
{
  __shared__ unsigned short As[64][264];       // +8 pad: conflict-free-ish
  __shared__ unsigned short Bs[NT * 16][264];
  const int tid = threadIdx.x;
  const int m0 = blockIdx.x * 64;

  if (AMODE == 2) {
#pragma unroll
    for (int j = 0; j < 8; ++j) {
      int flat = tid + j * 256;                 // 16B units, 2048 total
      int row = flat >> 5, seg = flat & 31;
      uint4 u = *(const uint4*)(Abf + (size_t)(m0 + row) * 256 + seg * 8);
      *(uint4*)&As[row][seg * 8] = u;
    }
  } else {
#pragma unroll
    for (int j = 0; j < 16; ++j) {
      int flat = tid + j * 256;                 // float4 units, 4096 total
      int row = flat >> 6, seg = flat & 63;
      size_t gi = (size_t)(m0 + row) * 256 + seg * 4;
      float4 a = *(const float4*)(Af0 + gi);
      if (AMODE == 1) {
        float4 b = *(const float4*)(Af1 + gi);
        a.x += b.x; a.y += b.y; a.z += b.z; a.w += b.w;
      }
      unsigned lo = (unsigned)f2bf(a.x) | ((unsigned)f2bf(a.y) << 16);
      unsigned hi = (unsigned)f2bf(a.z) | ((unsigned)f2bf(a.w) << 16);
      *(uint2*)&As[row][seg * 4] = make_uint2(lo, hi);
    }
  }

  const int wave = tid >> 6;
  const int lane = tid & 63;
  const int lr = lane & 15;       // A row / B col / D col
  const int lk = lane >> 4;       // k-group; D row group

#pragma unroll
  for (int ch = 0; ch < NCHUNK; ++ch) {
    const int n0 = ch * (NT * 16);
    __syncthreads();              // Bs free (also covers A staging on ch==0)
#pragma unroll
    for (int j = 0; j < NT * 2; ++j) {
      int flat = tid + j * 256;
      int row = flat >> 5, seg = flat & 31;
      uint4 u = *(const uint4*)(Bt + (size_t)(n0 + row) * 256 + seg * 8);
      *(uint4*)&Bs[row][seg * 8] = u;
    }
    __syncthreads();

    f32x4 acc[NT];
#pragma unroll
    for (int nt = 0; nt < NT; ++nt) acc[nt] = (f32x4){0.f, 0.f, 0.f, 0.f};
#pragma unroll
    for (int kt = 0; kt < 8; ++kt) {
      bf16x8 af = *(const bf16x8*)&As[wave * 16 + lr][kt * 32 + lk * 8];
#pragma unroll
      for (int nt = 0; nt < NT; ++nt) {
        bf16x8 bfr = *(const bf16x8*)&Bs[nt * 16 + lr][kt * 32 + lk * 8];
        acc[nt] = __builtin_amdgcn_mfma_f32_16x16x32_bf16(af, bfr, acc[nt], 0, 0, 0);
      }
    }

#pragma unroll
    for (int nt = 0; nt < NT; ++nt) {
      const int gcol = n0 + nt * 16 + lr;
      const float bv = bias[gcol];
#pragma unroll
      for (int r = 0; r < 4; ++r) {
        const int grow = m0 + wave * 16 + lk * 4 + r;
        float val = acc[nt][r] + bv;
        if (EPI == 0) {
          outb[(size_t)grow * 256 + gcol] = f2bf(val);
        } else if (EPI == 2) {
          size_t gi = (size_t)grow * 256 + gcol;
          outf[gi] = val + xres[gi];
        } else {
          if (gcol >= 64) {       // wave-uniform per (ch,nt): 16-col tiles
            float m1 = fmaxf(val, __shfl_xor(val, 1));
            float mx = fmaxf(m1, __shfl_xor(m1, 2));
            float e = __expf(val - mx);
            float s1 = e + __shfl_xor(e, 1);
            float s = s1 + __shfl_xor(s1, 2);
            val = e / s;
          }
          outf[(size_t)grow * 96 + gcol] = val;
        }
      }
    }
  }
}

// -------------------------------------------------------------- sample ------
// One thread = one (token, head). smp[t][0..63] raw offsets, [64..95] softmaxed
// attn. px = col + off_x, py = row + off_y (exact collapse of ref-point math).
// Bijective XCD swizzle: each XCD gets a contiguous band of image rows so its
// private L2 sees dense v-row reuse.
__global__ __launch_bounds__(256, 4) void sample_k(
    const unsigned short* __restrict__ vbf,    // [B][NTOK][256] bf16
    const float* __restrict__ smp,             // [ROWS][96]
    unsigned short* __restrict__ sampled)      // [ROWS][256] bf16
{
  const int NB = 2500, q = NB / 8, r = NB % 8;   // 312, 4
  int bid = blockIdx.x;
  int xcd = bid & 7, i = bid >> 3;
  int swz = (xcd < r) ? (xcd * (q + 1) + i)
                      : (r * (q + 1) + (xcd - r) * q + i);
  const int tid = swz * 256 + threadIdx.x;
  const int t = tid >> 3;
  const int h = tid & 7;
  const int b = t / NTOK;
  const int n = t - b * NTOK;
  const int ry = n / W_IMG;
  const int cx = n - ry * W_IMG;
  const float* sp = smp + (size_t)t * 96;
  const unsigned short* vb = vbf + (size_t)b * NTOK * 256 + h * 32;

  float acc[32];
#pragma unroll
  for (int i2 = 0; i2 < 32; ++i2) acc[i2] = 0.f;

#pragma unroll
  for (int p = 0; p < 4; ++p) {
    float ox = sp[h * 8 + p * 2 + 0];
    float oy = sp[h * 8 + p * 2 + 1];
    float aw = sp[64 + h * 4 + p];
    float px = (float)cx + ox;
    float py = (float)ry + oy;
    float fx = floorf(px), fy = floorf(py);
    int x0 = (int)fx, y0 = (int)fy;
    float lx = px - fx, ly = py - fy;
    float w00 = (1.f - lx) * (1.f - ly) * aw;
    float w10 = lx * (1.f - ly) * aw;
    float w01 = (1.f - lx) * ly * aw;
    float w11 = lx * ly * aw;
#pragma unroll
    for (int cc = 0; cc < 4; ++cc) {
      int ix = x0 + (cc & 1);
      int iy = y0 + (cc >> 1);
      float w = (cc == 0) ? w00 : (cc == 1) ? w10 : (cc == 2) ? w01 : w11;
      if (ix >= 0 && ix < W_IMG && iy >= 0 && iy < H_IMG) {
        const unsigned short* g = vb + (size_t)(iy * W_IMG + ix) * 256;
#pragma unroll
        for (int q2 = 0; q2 < 4; ++q2) {
          uint4 u = *(const uint4*)(g + q2 * 8);
          acc[q2 * 8 + 0] += w * bfl(u.x); acc[q2 * 8 + 1] += w * bfh(u.x);
          acc[q2 * 8 + 2] += w * bfl(u.y); acc[q2 * 8 + 3] += w * bfh(u.y);
          acc[q2 * 8 + 4] += w * bfl(u.z); acc[q2 * 8 + 5] += w * bfh(u.z);
          acc[q2 * 8 + 6] += w * bfl(u.w); acc[q2 * 8 + 7] += w * bfh(u.w);
        }
      }
    }
  }
  unsigned uo[16];
#pragma unroll
  for (int i2 = 0; i2 < 16; ++i2)
    uo[i2] = (unsigned)f2bf(acc[2 * i2]) | ((unsigned)f2bf(acc[2 * i2 + 1]) << 16);
  uint4* dst = (uint4*)(sampled + (size_t)t * 256 + h * 32);
  dst[0] = make_uint4(uo[0], uo[1], uo[2], uo[3]);
  dst[1] = make_uint4(uo[4], uo[5], uo[6], uo[7]);
  dst[2] = make_uint4(uo[8], uo[9], uo[10], uo[11]);
  dst[3] = make_uint4(uo[12], uo[13], uo[14], uo[15]);
}

// -------------------------------------------------------------- launch ------
extern "C" void kernel_launch(void* const* d_in, const int* in_sizes, int n_in,
                              void* d_out, int out_size, void* d_ws, size_t ws_size,
                              hipStream_t stream) {
  const float* x      = (const float*)d_in[0];
  const float* x_pos  = (const float*)d_in[1];
  const float* W_off  = (const float*)d_in[2];
  const float* b_off  = (const float*)d_in[3];
  const float* W_attn = (const float*)d_in[4];
  const float* b_attn = (const float*)d_in[5];
  const float* W_val  = (const float*)d_in[6];
  const float* b_val  = (const float*)d_in[7];
  const float* W_out  = (const float*)d_in[8];
  const float* b_out  = (const float*)d_in[9];
  float* out = (float*)d_out;

  char* ws = (char*)d_ws;
  unsigned short* Wv_t    = (unsigned short*)(ws);                 // 131072 B
  unsigned short* Wo_t    = (unsigned short*)(ws + 131072);        // 131072 B
  unsigned short* Wca_t   = (unsigned short*)(ws + 262144);        //  49152 B
  float*          biasc   = (float*)(ws + 311296);                 //    384 B
  unsigned short* vbf     = (unsigned short*)(ws + 311680);        // 40.96 MB
  float*          smp     = (float*)(ws + 41271680);               // 30.72 MB
  unsigned short* sampled = (unsigned short*)(ws + 71991680);      // 40.96 MB
  // total ws use: 112,951,680 B

  prep_weights<<<256, 256, 0, stream>>>(W_val, W_off, W_attn, W_out,
                                        b_off, b_attn, Wv_t, Wca_t, Wo_t, biasc);
  // v = x @ W_val + b_val  -> bf16
  gemm_wide<4, 4, 0, 0><<<1250, 256, 0, stream>>>(
      x, nullptr, nullptr, Wv_t, b_val, nullptr, nullptr, vbf);
  // proj = (x+x_pos) @ [W_off|W_attn] + biasc, softmax on attn cols -> f32
  gemm_wide<2, 3, 1, 1><<<1250, 256, 0, stream>>>(
      x, x_pos, nullptr, Wca_t, biasc, nullptr, smp, nullptr);
  // bilinear gather
  sample_k<<<2500, 256, 0, stream>>>(vbf, smp, sampled);
  // out = x + sampled @ W_out + b_out
  gemm_wide<4, 4, 2, 2><<<1250, 256, 0, stream>>>(
      nullptr, nullptr, sampled, Wo_t, b_out, x, out, nullptr);
}

// Round 5
// 331.357 us; speedup vs baseline: 1.2925x; 1.0957x over previous
//
#include <hip/hip_runtime.h>

#define H_IMG 200
#define W_IMG 200
#define NTOK  40000       // H*W
#define ROWS  80000       // B*N

typedef __attribute__((ext_vector_type(8))) short bf16x8;
typedef __attribute__((ext_vector_type(4))) float f32x4;

__device__ __forceinline__ unsigned short f2bf(float f) {
  unsigned u = __float_as_uint(f);
  u += 0x7fffu + ((u >> 16) & 1u);
  return (unsigned short)(u >> 16);
}
__device__ __forceinline__ float bfl(unsigned u) { return __uint_as_float(u << 16); }
__device__ __forceinline__ float bfh(unsigned u) { return __uint_as_float(u & 0xffff0000u); }

// ---------------------------------------------------------------- prep ------
__global__ __launch_bounds__(256) void prep_weights(
    const float* __restrict__ W_val, const float* __restrict__ W_off,
    const float* __restrict__ W_attn, const float* __restrict__ W_out,
    const float* __restrict__ b_off, const float* __restrict__ b_attn,
    unsigned short* __restrict__ Wv_t, unsigned short* __restrict__ Wca_t,
    unsigned short* __restrict__ Wo_t, float* __restrict__ biasc)
{
  int tid = blockIdx.x * 256 + threadIdx.x;   // 0..65535
  int n = tid >> 8, k = tid & 255;
  Wv_t[n * 256 + k] = f2bf(W_val[k * 256 + n]);
  Wo_t[n * 256 + k] = f2bf(W_out[k * 256 + n]);
  if (tid < 96 * 256) {
    float w = (n < 64) ? W_off[k * 64 + n] : W_attn[k * 32 + (n - 64)];
    Wca_t[tid] = f2bf(w);
  }
  if (tid < 96) biasc[tid] = (tid < 64) ? b_off[tid] : b_attn[tid - 64];
}

// ------------------------------------------------------------ v + proj ------
// Block: 64 rows. Stage As=bf16(x) once; v = As@Wv (4x64-col chunks, ->bf16);
// then in-place As += x_pos (bf16); proj = As@Wca (2x48-col chunks), softmax
// on attn cols, -> f32 smp.
__global__ __launch_bounds__(256, 2) void vproj_k(
    const float* __restrict__ x, const float* __restrict__ x_pos,
    const unsigned short* __restrict__ Wv_t,
    const unsigned short* __restrict__ Wca_t,
    const float* __restrict__ b_val, const float* __restrict__ biasc,
    unsigned short* __restrict__ vbf, float* __restrict__ smp)
{
  __shared__ unsigned short As[64][264];
  __shared__ unsigned short Bs[64][264];
  const int tid = threadIdx.x;
  const int m0 = blockIdx.x * 64;
  const int wave = tid >> 6, lane = tid & 63;
  const int lr = lane & 15, lk = lane >> 4;

#pragma unroll
  for (int j = 0; j < 16; ++j) {
    int flat = tid + j * 256;
    int row = flat >> 6, seg = flat & 63;
    float4 a = *(const float4*)(x + (size_t)(m0 + row) * 256 + seg * 4);
    unsigned lo = (unsigned)f2bf(a.x) | ((unsigned)f2bf(a.y) << 16);
    unsigned hi = (unsigned)f2bf(a.z) | ((unsigned)f2bf(a.w) << 16);
    *(uint2*)&As[row][seg * 4] = make_uint2(lo, hi);
  }

#pragma unroll
  for (int ch = 0; ch < 4; ++ch) {
    __syncthreads();              // As ready (ch0) / prev MFMA done (ch>0)
#pragma unroll
    for (int j = 0; j < 8; ++j) {
      int flat = tid + j * 256;
      int row = flat >> 5, seg = flat & 31;
      *(uint4*)&Bs[row][seg * 8] =
          *(const uint4*)(Wv_t + (size_t)(ch * 64 + row) * 256 + seg * 8);
    }
    __syncthreads();
    f32x4 acc[4];
#pragma unroll
    for (int nt = 0; nt < 4; ++nt) acc[nt] = (f32x4){0.f, 0.f, 0.f, 0.f};
#pragma unroll
    for (int kt = 0; kt < 8; ++kt) {
      bf16x8 af = *(const bf16x8*)&As[wave * 16 + lr][kt * 32 + lk * 8];
#pragma unroll
      for (int nt = 0; nt < 4; ++nt) {
        bf16x8 bfr = *(const bf16x8*)&Bs[nt * 16 + lr][kt * 32 + lk * 8];
        acc[nt] = __builtin_amdgcn_mfma_f32_16x16x32_bf16(af, bfr, acc[nt], 0, 0, 0);
      }
    }
#pragma unroll
    for (int nt = 0; nt < 4; ++nt) {
      const int gcol = ch * 64 + nt * 16 + lr;
      const float bv = b_val[gcol];
#pragma unroll
      for (int r = 0; r < 4; ++r) {
        const int grow = m0 + wave * 16 + lk * 4 + r;
        vbf[(size_t)grow * 256 + gcol] = f2bf(acc[nt][r] + bv);
      }
    }
  }

  __syncthreads();                // all v-MFMA reads of As done
#pragma unroll
  for (int j = 0; j < 16; ++j) {  // As := bf16( As + x_pos )
    int flat = tid + j * 256;
    int row = flat >> 6, seg = flat & 63;
    float4 p = *(const float4*)(x_pos + (size_t)(m0 + row) * 256 + seg * 4);
    uint2 cur = *(uint2*)&As[row][seg * 4];
    float v0 = bfl(cur.x) + p.x, v1 = bfh(cur.x) + p.y;
    float v2 = bfl(cur.y) + p.z, v3 = bfh(cur.y) + p.w;
    *(uint2*)&As[row][seg * 4] =
        make_uint2((unsigned)f2bf(v0) | ((unsigned)f2bf(v1) << 16),
                   (unsigned)f2bf(v2) | ((unsigned)f2bf(v3) << 16));
  }

#pragma unroll
  for (int ch = 0; ch < 2; ++ch) {
    __syncthreads();
#pragma unroll
    for (int j = 0; j < 6; ++j) {
      int flat = tid + j * 256;   // 48 rows x 32 segs = 1536
      int row = flat >> 5, seg = flat & 31;
      *(uint4*)&Bs[row][seg * 8] =
          *(const uint4*)(Wca_t + (size_t)(ch * 48 + row) * 256 + seg * 8);
    }
    __syncthreads();
    f32x4 acc[3];
#pragma unroll
    for (int nt = 0; nt < 3; ++nt) acc[nt] = (f32x4){0.f, 0.f, 0.f, 0.f};
#pragma unroll
    for (int kt = 0; kt < 8; ++kt) {
      bf16x8 af = *(const bf16x8*)&As[wave * 16 + lr][kt * 32 + lk * 8];
#pragma unroll
      for (int nt = 0; nt < 3; ++nt) {
        bf16x8 bfr = *(const bf16x8*)&Bs[nt * 16 + lr][kt * 32 + lk * 8];
        acc[nt] = __builtin_amdgcn_mfma_f32_16x16x32_bf16(af, bfr, acc[nt], 0, 0, 0);
      }
    }
#pragma unroll
    for (int nt = 0; nt < 3; ++nt) {
      const int gcol = ch * 48 + nt * 16 + lr;
      const float bv = biasc[gcol];
#pragma unroll
      for (int r = 0; r < 4; ++r) {
        const int grow = m0 + wave * 16 + lk * 4 + r;
        float val = acc[nt][r] + bv;
        if (gcol >= 64) {         // wave-uniform per (ch,nt)
          float m1 = fmaxf(val, __shfl_xor(val, 1));
          float mx = fmaxf(m1, __shfl_xor(m1, 2));
          float e = __expf(val - mx);
          float s1 = e + __shfl_xor(e, 1);
          float s = s1 + __shfl_xor(s1, 2);
          val = e / s;
        }
        smp[(size_t)grow * 96 + gcol] = val;
      }
    }
  }
}

// -------------------------------------------------- sample + out GEMM ------
// Block: 64 tokens (XCD-swizzled). Phase 1: 512 (token,head) bilinear samples
// -> LDS A-tile (branch-free clamped gathers, all loads in flight).
// Phase 2: out = x + As @ Wo_t + b_out.
__global__ __launch_bounds__(256, 2) void sampout_k(
    const unsigned short* __restrict__ vbf,    // [B][NTOK][256] bf16
    const float* __restrict__ smp,             // [ROWS][96]
    const unsigned short* __restrict__ Wo_t,
    const float* __restrict__ b_out, const float* __restrict__ x,
    float* __restrict__ out)
{
  __shared__ unsigned short As[64][264];
  __shared__ unsigned short Bs[64][264];
  const int tid = threadIdx.x;
  // bijective XCD swizzle over 1250 blocks (q=156, r=2)
  int bid = blockIdx.x;
  int xcd = bid & 7, ii = bid >> 3;
  int swz = (xcd < 2) ? xcd * 157 + ii : 2 * 157 + (xcd - 2) * 156 + ii;
  const int tok0 = swz * 64;

#pragma unroll
  for (int pp = 0; pp < 2; ++pp) {
    const int pair = tid + pp * 256;
    const int lt = pair >> 3, h = pair & 7;
    const int t = tok0 + lt;
    const int b = t / NTOK;
    const int n = t - b * NTOK;
    const int ry = n / W_IMG, cx = n - ry * W_IMG;
    const float* sp = smp + (size_t)t * 96;
    float4 o01 = *(const float4*)(sp + h * 8);
    float4 o23 = *(const float4*)(sp + h * 8 + 4);
    float4 aw4 = *(const float4*)(sp + 64 + h * 4);
    const unsigned short* vb = vbf + (size_t)b * NTOK * 256 + h * 32;

    float offs[8] = {o01.x, o01.y, o01.z, o01.w, o23.x, o23.y, o23.z, o23.w};
    float aws[4] = {aw4.x, aw4.y, aw4.z, aw4.w};

    const unsigned short* gp[16];
    float wv[16];
#pragma unroll
    for (int p = 0; p < 4; ++p) {
      float px = (float)cx + offs[2 * p];
      float py = (float)ry + offs[2 * p + 1];
      float fx = floorf(px), fy = floorf(py);
      int x0 = (int)fx, y0 = (int)fy;
      float lx = px - fx, ly = py - fy;
      float cw[4] = {(1.f - lx) * (1.f - ly), lx * (1.f - ly),
                     (1.f - lx) * ly, lx * ly};
#pragma unroll
      for (int cc = 0; cc < 4; ++cc) {
        int ix = x0 + (cc & 1), iy = y0 + (cc >> 1);
        int ixc = ix < 0 ? 0 : (ix > W_IMG - 1 ? W_IMG - 1 : ix);
        int iyc = iy < 0 ? 0 : (iy > H_IMG - 1 ? H_IMG - 1 : iy);
        float w = cw[cc] * aws[p];
        gp[p * 4 + cc] = vb + (size_t)(iyc * W_IMG + ixc) * 256;
        wv[p * 4 + cc] = (ix == ixc && iy == iyc) ? w : 0.f;
      }
    }
    float acc[32];
#pragma unroll
    for (int i = 0; i < 32; ++i) acc[i] = 0.f;
#pragma unroll
    for (int s = 0; s < 16; ++s) {
      const uint4* g = (const uint4*)gp[s];
      float w = wv[s];
      uint4 u0 = g[0], u1 = g[1], u2 = g[2], u3 = g[3];
      acc[0]  += w * bfl(u0.x); acc[1]  += w * bfh(u0.x);
      acc[2]  += w * bfl(u0.y); acc[3]  += w * bfh(u0.y);
      acc[4]  += w * bfl(u0.z); acc[5]  += w * bfh(u0.z);
      acc[6]  += w * bfl(u0.w); acc[7]  += w * bfh(u0.w);
      acc[8]  += w * bfl(u1.x); acc[9]  += w * bfh(u1.x);
      acc[10] += w * bfl(u1.y); acc[11] += w * bfh(u1.y);
      acc[12] += w * bfl(u1.z); acc[13] += w * bfh(u1.z);
      acc[14] += w * bfl(u1.w); acc[15] += w * bfh(u1.w);
      acc[16] += w * bfl(u2.x); acc[17] += w * bfh(u2.x);
      acc[18] += w * bfl(u2.y); acc[19] += w * bfh(u2.y);
      acc[20] += w * bfl(u2.z); acc[21] += w * bfh(u2.z);
      acc[22] += w * bfl(u2.w); acc[23] += w * bfh(u2.w);
      acc[24] += w * bfl(u3.x); acc[25] += w * bfh(u3.x);
      acc[26] += w * bfl(u3.y); acc[27] += w * bfh(u3.y);
      acc[28] += w * bfl(u3.z); acc[29] += w * bfh(u3.z);
      acc[30] += w * bfl(u3.w); acc[31] += w * bfh(u3.w);
    }
    unsigned uo[16];
#pragma unroll
    for (int i = 0; i < 16; ++i)
      uo[i] = (unsigned)f2bf(acc[2 * i]) | ((unsigned)f2bf(acc[2 * i + 1]) << 16);
    uint4* dst = (uint4*)&As[lt][h * 32];
    dst[0] = make_uint4(uo[0], uo[1], uo[2], uo[3]);
    dst[1] = make_uint4(uo[4], uo[5], uo[6], uo[7]);
    dst[2] = make_uint4(uo[8], uo[9], uo[10], uo[11]);
    dst[3] = make_uint4(uo[12], uo[13], uo[14], uo[15]);
  }

  const int wave = tid >> 6, lane = tid & 63;
  const int lr = lane & 15, lk = lane >> 4;
#pragma unroll
  for (int ch = 0; ch < 4; ++ch) {
    if (ch) __syncthreads();      // prev chunk's MFMA done before Bs restage
#pragma unroll
    for (int j = 0; j < 8; ++j) {
      int flat = tid + j * 256;
      int row = flat >> 5, seg = flat & 31;
      *(uint4*)&Bs[row][seg * 8] =
          *(const uint4*)(Wo_t + (size_t)(ch * 64 + row) * 256 + seg * 8);
    }
    __syncthreads();              // As (sampling) + Bs ready
    f32x4 acc[4];
#pragma unroll
    for (int nt = 0; nt < 4; ++nt) acc[nt] = (f32x4){0.f, 0.f, 0.f, 0.f};
#pragma unroll
    for (int kt = 0; kt < 8; ++kt) {
      bf16x8 af = *(const bf16x8*)&As[wave * 16 + lr][kt * 32 + lk * 8];
#pragma unroll
      for (int nt = 0; nt < 4; ++nt) {
        bf16x8 bfr = *(const bf16x8*)&Bs[nt * 16 + lr][kt * 32 + lk * 8];
        acc[nt] = __builtin_amdgcn_mfma_f32_16x16x32_bf16(af, bfr, acc[nt], 0, 0, 0);
      }
    }
#pragma unroll
    for (int nt = 0; nt < 4; ++nt) {
      const int gcol = ch * 64 + nt * 16 + lr;
      const float bv = b_out[gcol];
#pragma unroll
      for (int r = 0; r < 4; ++r) {
        const int grow = tok0 + wave * 16 + lk * 4 + r;
        size_t gi = (size_t)grow * 256 + gcol;
        out[gi] = acc[nt][r] + bv + x[gi];
      }
    }
  }
}

// -------------------------------------------------------------- launch ------
extern "C" void kernel_launch(void* const* d_in, const int* in_sizes, int n_in,
                              void* d_out, int out_size, void* d_ws, size_t ws_size,
                              hipStream_t stream) {
  const float* x      = (const float*)d_in[0];
  const float* x_pos  = (const float*)d_in[1];
  const float* W_off  = (const float*)d_in[2];
  const float* b_off  = (const float*)d_in[3];
  const float* W_attn = (const float*)d_in[4];
  const float* b_attn = (const float*)d_in[5];
  const float* W_val  = (const float*)d_in[6];
  const float* b_val  = (const float*)d_in[7];
  const float* W_out  = (const float*)d_in[8];
  const float* b_out  = (const float*)d_in[9];
  float* out = (float*)d_out;

  char* ws = (char*)d_ws;
  unsigned short* Wv_t  = (unsigned short*)(ws);                 // 131072 B
  unsigned short* Wo_t  = (unsigned short*)(ws + 131072);        // 131072 B
  unsigned short* Wca_t = (unsigned short*)(ws + 262144);        //  49152 B
  float*          biasc = (float*)(ws + 311296);                 //    384 B
  unsigned short* vbf   = (unsigned short*)(ws + 311680);        // 40.96 MB
  float*          smp   = (float*)(ws + 41271680);               // 30.72 MB
  // total ws use: 71,991,680 B

  prep_weights<<<256, 256, 0, stream>>>(W_val, W_off, W_attn, W_out,
                                        b_off, b_attn, Wv_t, Wca_t, Wo_t, biasc);
  vproj_k<<<1250, 256, 0, stream>>>(x, x_pos, Wv_t, Wca_t, b_val, biasc,
                                    vbf, smp);
  sampout_k<<<1250, 256, 0, stream>>>(vbf, smp, Wo_t, b_out, x, out);
}